// Round 4
// 9161.716 us; speedup vs baseline: 1.8185x; 1.8185x over previous
//
#include <hip/hip_runtime.h>

// Problem constants
#define V_SZ 32000
#define E_SZ 256
#define H_SZ 512
#define B_SZ 32
#define S_SRC 128
#define T_STEPS 128   // T_TGT-1

// ---------------------------------------------------------------------------
// Grid barrier with explicit CDNA4 cache maintenance (grid.sync semantics,
// flat monotonic-counter protocol):
//   1. every wave drains its stores to L2 (vector L1 is write-through)
//   2. thread 0: buffer_wbl2 sc1  -> push dirty L2 lines to coherent point
//   3. thread 0: global_atomic_add sc1 (bypasses XCD L2) + spin on
//      global_load sc0 sc1 (reads the coherent point)
//   4. thread 0: buffer_inv sc0 sc1 -> invalidate stale L1/L2 for this CU/XCD
// Rounds 2-3 failed because relaxed HIP atomics emit NO sc bits and no
// fences -> cross-XCD staleness. Explicit asm removes all mapping ambiguity.
// ---------------------------------------------------------------------------
__device__ __forceinline__ void gbar(int* cnt, int target) {
    asm volatile("s_waitcnt vmcnt(0) lgkmcnt(0)" ::: "memory");
    __syncthreads();
    if (threadIdx.x == 0) {
        // release: write back dirty L2 to the coherent point, wait done
        asm volatile("buffer_wbl2 sc1\n\t"
                     "s_waitcnt vmcnt(0)" ::: "memory");
        // arrive: counter RMW routed past the XCD L2
        asm volatile("global_atomic_add %0, %1, off sc1"
                     :: "v"(cnt), "v"(1) : "memory");
        // wait: spin on a coherent-point load
        int v;
        do {
            __builtin_amdgcn_s_sleep(2);
            asm volatile("global_load_dword %0, %1, off sc0 sc1\n\t"
                         "s_waitcnt vmcnt(0)"
                         : "=v"(v) : "v"(cnt) : "memory");
        } while (v < target);
        // acquire: drop stale L1/L2 lines before anyone reads data
        asm volatile("buffer_inv sc0 sc1\n\t"
                     "s_waitcnt vmcnt(0)" ::: "memory");
    }
    __syncthreads();
}

// ---------------------------------------------------------------------------
// Gather: embT[t][e][b] = emb[ids[b][t]][e]   (t<128, ids has 129 cols)
// Also zeroes the grid-barrier counter (lives in d_out[0], see launch).
// ---------------------------------------------------------------------------
__global__ __launch_bounds__(256) void gather_embT(
    const float* __restrict__ emb, const int* __restrict__ ids,
    float* __restrict__ embT, int* __restrict__ bar)
{
    if (blockIdx.x == 0 && threadIdx.x == 0) bar[0] = 0;
    const int bx = blockIdx.x;
    const int t = bx >> 5, ec = bx & 31;
    const int tid = threadIdx.x;
    const int e_l = tid >> 5, b = tid & 31;
    const int e = (ec << 3) + e_l;
    const int id = ids[b * 129 + t];
    embT[t * 8192 + (ec << 8) + tid] = emb[id * 256 + e];
}

// ---------------------------------------------------------------------------
// NT GEMM: C[m][n] = sum_k A[m][k]*B[n][k] (+bias[n]); 64x64 tile, 4x4 micro
// ---------------------------------------------------------------------------
__global__ __launch_bounds__(256) void ntgemm(
    const float* __restrict__ A, const float* __restrict__ B,
    float* __restrict__ C, const float* __restrict__ bias,
    int K, int lda, int ldb, int ldc,
    long sA, long sB, long sC)
{
    const int bz = blockIdx.z;
    A += (long)bz * sA; B += (long)bz * sB; C += (long)bz * sC;
    const int m0 = blockIdx.y << 6, n0 = blockIdx.x << 6;
    const int tid = threadIdx.x;
    const int tx = tid & 15, ty = tid >> 4;
    const int arow = tid >> 2, akq = tid & 3;

    __shared__ __align__(16) float At[16 * 68];
    __shared__ __align__(16) float Bt[16 * 68];

    float acc[4][4];
#pragma unroll
    for (int i = 0; i < 4; ++i)
#pragma unroll
        for (int j = 0; j < 4; ++j) acc[i][j] = 0.f;

    for (int k0 = 0; k0 < K; k0 += 16) {
        const float4 av = *(const float4*)&A[(long)(m0 + arow) * lda + k0 + (akq << 2)];
        const float4 bv = *(const float4*)&B[(long)(n0 + arow) * ldb + k0 + (akq << 2)];
        __syncthreads();
        At[((akq << 2) + 0) * 68 + arow] = av.x;
        At[((akq << 2) + 1) * 68 + arow] = av.y;
        At[((akq << 2) + 2) * 68 + arow] = av.z;
        At[((akq << 2) + 3) * 68 + arow] = av.w;
        Bt[((akq << 2) + 0) * 68 + arow] = bv.x;
        Bt[((akq << 2) + 1) * 68 + arow] = bv.y;
        Bt[((akq << 2) + 2) * 68 + arow] = bv.z;
        Bt[((akq << 2) + 3) * 68 + arow] = bv.w;
        __syncthreads();
#pragma unroll
        for (int kk = 0; kk < 16; ++kk) {
            const float4 a4 = *(const float4*)&At[kk * 68 + (ty << 2)];
            const float4 b4 = *(const float4*)&Bt[kk * 68 + (tx << 2)];
            const float a[4] = {a4.x, a4.y, a4.z, a4.w};
            const float b[4] = {b4.x, b4.y, b4.z, b4.w};
#pragma unroll
            for (int i = 0; i < 4; ++i)
#pragma unroll
                for (int j = 0; j < 4; ++j) acc[i][j] = fmaf(a[i], b[j], acc[i][j]);
        }
    }

    float4 bb = make_float4(0.f, 0.f, 0.f, 0.f);
    if (bias) bb = *(const float4*)&bias[n0 + (tx << 2)];
#pragma unroll
    for (int i = 0; i < 4; ++i) {
        float4 o;
        o.x = acc[i][0] + bb.x; o.y = acc[i][1] + bb.y;
        o.z = acc[i][2] + bb.z; o.w = acc[i][3] + bb.w;
        *(float4*)&C[(long)(m0 + (ty << 2) + i) * ldc + n0 + (tx << 2)] = o;
    }
}

// ---------------------------------------------------------------------------
// Cooperative scan kernel. grid = 256 WGs x 256 threads. WG w owns hidden
// dims jj = {2w, 2w+1}. LDS-persistent gate weights. Cross-WG state uses
// plain loads/stores; visibility is provided by gbar's explicit
// wbl2/inv fences (same semantics as grid.sync, cheaper protocol).
// ---------------------------------------------------------------------------
__global__ __launch_bounds__(256, 1) void scan_kernel(
    const float* __restrict__ embT, const float* __restrict__ keysT,
    const float* __restrict__ PT,
    float* __restrict__ hT, float* __restrict__ oT,
    float* __restrict__ h_nat, float* __restrict__ scoresW,
    float* __restrict__ o_seq,
    const float* __restrict__ Wih, const float* __restrict__ bih,
    const float* __restrict__ Whh, const float* __restrict__ bhh,
    const float* __restrict__ Wdec, const float* __restrict__ bdecg,
    const int* __restrict__ mask,
    const float* __restrict__ h0, const float* __restrict__ c0,
    int* __restrict__ bar)
{
    const int w = blockIdx.x;
    const int tid = threadIdx.x;

    __shared__ __align__(16) float wrow[8 * 1288];   // [g*2+jl][k] k<768: Wih, k>=768: Whh
    __shared__ __align__(16) float wd2s[2 * 520];    // W_dec[:,1024:1536] rows
    __shared__ float blds[8];
    __shared__ float bdecs[2];
    __shared__ float c_lds[64];                      // [jl*32+b]
    __shared__ __align__(16) float scratch[4832];    // phase-unioned

    // ---- load persistent weights ----
#pragma unroll 1
    for (int rr = 0; rr < 8; ++rr) {
        const int g = rr >> 1, jl = rr & 1;
        const int j = g * 512 + (w << 1) + jl;
        for (int idx = tid; idx < 768; idx += 256) wrow[rr * 1288 + idx] = Wih[j * 768 + idx];
        for (int idx = tid; idx < 512; idx += 256) wrow[rr * 1288 + 768 + idx] = Whh[j * 512 + idx];
        if (tid == 0) blds[rr] = bih[j] + bhh[j];
    }
#pragma unroll 1
    for (int jl = 0; jl < 2; ++jl) {
        const int j = (w << 1) + jl;
        for (int idx = tid; idx < 512; idx += 256) wd2s[jl * 520 + idx] = Wdec[j * 1536 + 1024 + idx];
        if (tid == 0) bdecs[jl] = bdecg[j];
    }
    if (tid < 64) {
        const int fb = tid & 31, jl = tid >> 5;
        const int jj = (w << 1) + jl;
        c_lds[jl * 32 + fb] = c0[fb * 512 + jj];
        hT[jj * 32 + fb] = h0[fb * 512 + jj];
        oT[jj * 32 + fb] = 0.f;
    }
    int bt = 0;
    gbar(bar, (++bt) << 8);

    for (int t = 0; t < T_STEPS; ++t) {
        const int cur = t & 1, nxt = cur ^ 1;

        // ================= Phase A: gates -> c,h =================
        {
            const int b = tid & 31, r = tid >> 5;
            float acc[8];
#pragma unroll
            for (int rr = 0; rr < 8; ++rr) acc[rr] = 0.f;
            const int kstart = r * 160;
#pragma unroll 1
            for (int blk = 0; blk < 5; ++blk) {
                const int kg = kstart + blk * 32;
                const float* src;
                if (kg < 256)      src = embT + t * 8192 + kg * 32 + b;
                else if (kg < 768) src = oT + cur * 16384 + (kg - 256) * 32 + b;
                else               src = hT + cur * 16384 + (kg - 768) * 32 + b;
#pragma unroll
                for (int kk = 0; kk < 32; kk += 4) {
                    const float x0 = src[(kk + 0) * 32];
                    const float x1 = src[(kk + 1) * 32];
                    const float x2 = src[(kk + 2) * 32];
                    const float x3 = src[(kk + 3) * 32];
                    const int kw = kg + kk;
#pragma unroll
                    for (int rr = 0; rr < 8; ++rr) {
                        const float4 w4 = *(const float4*)&wrow[rr * 1288 + kw];
                        acc[rr] = fmaf(x0, w4.x, fmaf(x1, w4.y, fmaf(x2, w4.z, fmaf(x3, w4.w, acc[rr]))));
                    }
                }
            }
#pragma unroll
            for (int rr = 0; rr < 8; ++rr) scratch[(b * 8 + r) * 9 + rr] = acc[rr];
        }
        __syncthreads();
        if (tid < 64) {
            const int fb = tid & 31, jl = tid >> 5;
            float gv[4];
#pragma unroll
            for (int g = 0; g < 4; ++g) {
                float s = blds[g * 2 + jl];
#pragma unroll
                for (int r2 = 0; r2 < 8; ++r2) s += scratch[(fb * 8 + r2) * 9 + g * 2 + jl];
                gv[g] = s;
            }
            const float ig = 1.f / (1.f + __expf(-gv[0]));
            const float fg = 1.f / (1.f + __expf(-gv[1]));
            const float gg = tanhf(gv[2]);
            const float og = 1.f / (1.f + __expf(-gv[3]));
            const int ci = jl * 32 + fb;
            const float cn = fmaf(fg, c_lds[ci], ig * gg);
            const float hn = og * tanhf(cn);
            c_lds[ci] = cn;
            const int jj = (w << 1) + jl;
            hT[nxt * 16384 + jj * 32 + fb] = hn;
            h_nat[fb * 512 + jj] = hn;
        }
        gbar(bar, (++bt) << 8);

        // ================= Phase B1: scores = h_new . keys =================
        {
            const int bb = w >> 3, sl = w & 7;
            float* hs = scratch;            // 512
            float* spart = scratch + 512;   // 16*17
            hs[tid] = h_nat[bb * 512 + tid];
            hs[256 + tid] = h_nat[bb * 512 + 256 + tid];
            __syncthreads();
            const int s_l = tid & 15, kp = tid >> 4;
            const int s = sl * 16 + s_l;
            const float* kcol = keysT + (bb * 512 + kp * 32) * 128 + s;
            float a = 0.f;
#pragma unroll
            for (int k = 0; k < 32; ++k) a = fmaf(hs[kp * 32 + k], kcol[k * 128], a);
            spart[s_l * 17 + kp] = a;
            __syncthreads();
            if (tid < 16) {
                float v = 0.f;
#pragma unroll
                for (int kp2 = 0; kp2 < 16; ++kp2) v += spart[tid * 17 + kp2];
                const int ss = sl * 16 + tid;
                v += (mask[bb * 128 + ss] > 0) ? 0.f : -1000000000.0f;
                scoresW[bb * 128 + ss] = v;
            }
        }
        gbar(bar, (++bt) << 8);

        // ================= Phase B2: softmax + o_new =================
        {
            float* sc = scratch;            // 32*132
            float* red = scratch + 4224;    // 32*9
            float* opart = scratch + 4512;  // 32*2*5
#pragma unroll
            for (int i = 0; i < 16; ++i) {
                const int idx = i * 256 + tid;
                sc[(idx >> 7) * 132 + (idx & 127)] = scoresW[idx];
            }
            __syncthreads();
            const int rb = tid >> 3, sub = tid & 7;
            float lm = -1e30f;
#pragma unroll
            for (int i = 0; i < 16; ++i) lm = fmaxf(lm, sc[rb * 132 + sub * 16 + i]);
            red[rb * 9 + sub] = lm;
            __syncthreads();
            if (sub == 0) {
                float m = red[rb * 9];
#pragma unroll
                for (int q = 1; q < 8; ++q) m = fmaxf(m, red[rb * 9 + q]);
                red[rb * 9 + 8] = m;
            }
            __syncthreads();
            const float m = red[rb * 9 + 8];
            float ls = 0.f;
#pragma unroll
            for (int i = 0; i < 16; ++i) {
                const int idx = rb * 132 + sub * 16 + i;
                const float e = __expf(sc[idx] - m);
                sc[idx] = e;
                ls += e;
            }
            red[rb * 9 + sub] = ls;
            __syncthreads();
            if (sub == 0) {
                float l = 0.f;
#pragma unroll
                for (int q = 0; q < 8; ++q) l += red[rb * 9 + q];
                red[rb * 9 + 8] = 1.f / l;   // m no longer needed
            }
            __syncthreads();
            const float inv = red[rb * 9 + 8];
#pragma unroll
            for (int i = 0; i < 16; ++i) sc[rb * 132 + sub * 16 + i] *= inv;
            __syncthreads();

            // partial o_new: attn.P (over s) + h.WdecH (over k), split 4 ways
            const int pb = tid >> 3, jl = (tid >> 2) & 1, pp = tid & 3;
            const int j = (w << 1) + jl;
            float accp = 0.f;
            {
                const float* prow = PT + (pb * 512 + j) * 128 + pp * 32;
                const float* at = &sc[pb * 132 + pp * 32];
#pragma unroll
                for (int s4 = 0; s4 < 32; s4 += 4) {
                    const float4 p4 = *(const float4*)(prow + s4);
                    const float4 a4 = *(const float4*)(at + s4);
                    accp = fmaf(p4.x, a4.x, fmaf(p4.y, a4.y, fmaf(p4.z, a4.z, fmaf(p4.w, a4.w, accp))));
                }
            }
            {
                const float* hrow = h_nat + (pb << 9) + pp * 128;
                const float* w2 = &wd2s[jl * 520 + pp * 128];
#pragma unroll
                for (int k4 = 0; k4 < 128; k4 += 4) {
                    const float4 h4 = *(const float4*)(hrow + k4);
                    const float4 wv = *(const float4*)(w2 + k4);
                    accp = fmaf(h4.x, wv.x, fmaf(h4.y, wv.y, fmaf(h4.z, wv.z, fmaf(h4.w, wv.w, accp))));
                }
            }
            opart[(pb * 2 + jl) * 5 + pp] = accp;
            __syncthreads();
            if (tid < 64) {
                const int fb = tid >> 1, jl2 = tid & 1;
                float v = 0.f;
#pragma unroll
                for (int q = 0; q < 4; ++q) v += opart[(fb * 2 + jl2) * 5 + q];
                const float o = tanhf(v + bdecs[jl2]);
                const int jj = (w << 1) + jl2;
                oT[nxt * 16384 + jj * 32 + fb] = o;
                o_seq[(fb * 128 + t) * 512 + jj] = o;
            }
        }
        gbar(bar, (++bt) << 8);
    }
}

// ---------------------------------------------------------------------------
// In-place log_softmax over rows of 32000. One WG per row.
// ---------------------------------------------------------------------------
__global__ __launch_bounds__(256) void lsm_kernel(float* __restrict__ out)
{
    const long base = (long)blockIdx.x * 32000;
    const int tid = threadIdx.x;
    __shared__ float rm[4], rs[4];

    float m = -1e30f;
    for (int i = tid * 4; i < 32000; i += 1024) {
        const float4 v = *(const float4*)&out[base + i];
        m = fmaxf(m, fmaxf(fmaxf(v.x, v.y), fmaxf(v.z, v.w)));
    }
#pragma unroll
    for (int off = 32; off; off >>= 1) m = fmaxf(m, __shfl_xor(m, off));
    if ((tid & 63) == 0) rm[tid >> 6] = m;
    __syncthreads();
    m = fmaxf(fmaxf(rm[0], rm[1]), fmaxf(rm[2], rm[3]));

    float s = 0.f;
    for (int i = tid * 4; i < 32000; i += 1024) {
        const float4 v = *(const float4*)&out[base + i];
        s += __expf(v.x - m) + __expf(v.y - m) + __expf(v.z - m) + __expf(v.w - m);
    }
#pragma unroll
    for (int off = 32; off; off >>= 1) s += __shfl_xor(s, off);
    if ((tid & 63) == 0) rs[tid >> 6] = s;
    __syncthreads();
    s = rs[0] + rs[1] + rs[2] + rs[3];
    const float lse = m + logf(s);

    for (int i = tid * 4; i < 32000; i += 1024) {
        float4 v = *(const float4*)&out[base + i];
        v.x -= lse; v.y -= lse; v.z -= lse; v.w -= lse;
        *(float4*)&out[base + i] = v;
    }
}

// ---------------------------------------------------------------------------
extern "C" void kernel_launch(void* const* d_in, const int* in_sizes, int n_in,
                              void* d_out, int out_size, void* d_ws, size_t ws_size,
                              hipStream_t stream)
{
    const float* enc  = (const float*)d_in[0];
    const int*   mask = (const int*)d_in[1];
    const int*   ids  = (const int*)d_in[2];
    const float* h0   = (const float*)d_in[3];
    const float* c0   = (const float*)d_in[4];
    const float* emb  = (const float*)d_in[5];
    const float* Wih  = (const float*)d_in[6];
    const float* bih  = (const float*)d_in[7];
    const float* Whh  = (const float*)d_in[8];
    const float* bhh  = (const float*)d_in[9];
    const float* Watt = (const float*)d_in[10];
    const float* Wdec = (const float*)d_in[11];
    const float* bdec = (const float*)d_in[12];
    const float* Wvoc = (const float*)d_in[13];
    const float* bvoc = (const float*)d_in[14];
    float* out = (float*)d_out;

    float* ws = (float*)d_ws;
    float* embT    = ws;                       // 128*256*32   = 1,048,576
    float* keysT   = embT + 1048576;           // 32*512*128   = 2,097,152
    float* PT      = keysT + 2097152;          // 32*512*128   = 2,097,152
    float* hT      = PT + 2097152;             // 2*512*32     = 32,768
    float* oT      = hT + 32768;               // 2*512*32     = 32,768
    float* h_nat   = oT + 32768;               // 32*512       = 16,384
    float* scoresW = h_nat + 16384;            // 32*128       = 4,096
    float* o_seq   = scoresW + 4096;           // 32*128*512   = 2,097,152

    // Barrier counter lives in d_out[0]: allocated, untouched until the vocab
    // GEMM (stream-ordered after the scan) and fully overwritten afterward.
    int* bar = (int*)d_out;

    // 1) embedding gather into transposed layout (also zeroes barrier counter)
    gather_embT<<<dim3(128 * 32), dim3(256), 0, stream>>>(emb, ids, embT, bar);

    // 2) keysT[b][h][s] = sum_k W_att[h,k] * enc[b,s,k]
    ntgemm<<<dim3(2, 8, 32), dim3(256), 0, stream>>>(
        Watt, enc, keysT, nullptr, 1024, 1024, 1024, 128,
        0L, 131072L, 65536L);

    // 3) PT[b][j][s] = sum_k W_dec[j,k<1024] * enc[b,s,k]
    ntgemm<<<dim3(2, 8, 32), dim3(256), 0, stream>>>(
        Wdec, enc, PT, nullptr, 1024, 1536, 1024, 128,
        0L, 131072L, 65536L);

    // 4) cooperative recurrent scan (cooperative launch for co-residency;
    //    synchronization via the fence-correct flat-counter barrier)
    void* args[] = {
        (void*)&embT, (void*)&keysT, (void*)&PT,
        (void*)&hT, (void*)&oT, (void*)&h_nat, (void*)&scoresW, (void*)&o_seq,
        (void*)&Wih, (void*)&bih, (void*)&Whh, (void*)&bhh,
        (void*)&Wdec, (void*)&bdec, (void*)&mask, (void*)&h0, (void*)&c0,
        (void*)&bar
    };
    hipLaunchCooperativeKernel((void*)scan_kernel, dim3(256), dim3(256),
                               args, 0, stream);

    // 5) logits = o_seq @ W_vocab^T + b_vocab  (written straight to d_out)
    ntgemm<<<dim3(500, 64, 1), dim3(256), 0, stream>>>(
        o_seq, Wvoc, out, bvoc, 512, 512, 512, 32000, 0L, 0L, 0L);

    // 6) in-place log_softmax
    lsm_kernel<<<dim3(4096), dim3(256), 0, stream>>>(out);
}